// Round 7
// baseline (48.601 us; speedup 1.0000x reference)
//
#include <hip/hip_runtime.h>

// QDFRCell fused: out = fq(relu(fq(xq*qmask,0,2) + prev - fq(0.2*prev,0,2)), 0, 2)
// x:[16384,1] f32, prev:[16384,2048] f32, mask:[1,2048] f32 -> out:[16384,2048] f32
//
// Round 6 profile: warm FETCH_SIZE = 66 MB (half of prev L3-resident!) ->
// HBM only 4.4 TB/s, NOT at the wall. Eviction arithmetic: prev 134 MB +
// out 134 MB write-alloc = 268 > 256 MB MALL -> ~50% survival.
// Round 7: CACHE PARTITIONING — first 14336 rows (112 MiB) of prev load
// temporal (retained), last 2048 rows (16 MiB) load NT (stream, no alloc).
// Pressure = 112 + 134 = 246 MiB < 256 -> temporal region survives replays.
// Predict warm FETCH ~20-30 MB, dur 45 -> ~30-36 us. Null -> roofline.

constexpr int NN  = 2048;
constexpr int N4  = NN / 4;          // 512 float4 per row
constexpr int RPB = 8;               // rows per block
constexpr int ROWS_TEMPORAL = 14336; // 112 MiB of prev kept MALL-resident

typedef float vf4 __attribute__((ext_vector_type(4)));

__global__ __launch_bounds__(512) void qdfr_fused(const float* __restrict__ x,
                                                  const float* __restrict__ prev,
                                                  const float* __restrict__ mask,
                                                  float* __restrict__ out) {
    constexpr float IN_SCALE = 0.497f / 255.0f;
    constexpr float INV_IN   = 1.0f / (0.497f / 255.0f);
    constexpr float L_SCALE  = 2.0f / 255.0f;
    constexpr float INV_L    = 1.0f / (2.0f / 255.0f);

    const int t    = threadIdx.x;
    const int row0 = blockIdx.x * RPB;

    // Partitioned cache policy (block-uniform branch, no divergence):
    // head of prev -> temporal (allocate in MALL, survives replays);
    // tail of prev -> non-temporal (stream, don't add allocation pressure).
    vf4 p[RPB];
    if (row0 < ROWS_TEMPORAL) {
        #pragma unroll
        for (int r = 0; r < RPB; ++r)
            p[r] = ((const vf4*)prev)[(long)(row0 + r) * N4 + t];
    } else {
        #pragma unroll
        for (int r = 0; r < RPB; ++r)
            p[r] = __builtin_nontemporal_load((const vf4*)prev + (long)(row0 + r) * N4 + t);
    }

    // Thread t consumes exactly mask4[t]; same registers feed the reduction.
    const vf4 m = ((const vf4*)mask)[t];

    float mn = fminf(fminf(m.x, m.y), fminf(m.z, m.w));
    float mx = fmaxf(fmaxf(m.x, m.y), fmaxf(m.z, m.w));
    #pragma unroll
    for (int d = 1; d < 64; d <<= 1) {
        mn = fminf(mn, __shfl_xor(mn, d));
        mx = fmaxf(mx, __shfl_xor(mx, d));
    }
    __shared__ float red[16];
    const int wave = t >> 6;
    if ((t & 63) == 0) { red[wave * 2] = mn; red[wave * 2 + 1] = mx; }
    __syncthreads();
    mn = red[0];
    mx = red[1];
    #pragma unroll
    for (int w = 1; w < 8; ++w) {
        mn = fminf(mn, red[w * 2]);
        mx = fmaxf(mx, red[w * 2 + 1]);
    }

    const float mscale = (mx - mn) / 255.0f;   // bit-exact vs reference expr
    const float minv   = 1.0f / mscale;

    // Quantize this thread's mask element once (shared by all 8 rows).
    vf4 qm;
    qm.x = rintf((m.x - mn) * minv) * mscale + mn;
    qm.y = rintf((m.y - mn) * minv) * mscale + mn;
    qm.z = rintf((m.z - mn) * minv) * mscale + mn;
    qm.w = rintf((m.w - mn) * minv) * mscale + mn;

    #pragma unroll
    for (int r = 0; r < RPB; ++r) {
        // fake_quant(x[row], 0, 0.497) — block-uniform scalar
        const float xv = x[row0 + r];
        const float xc = fminf(fmaxf(xv, 0.0f), 0.497f);
        const float xq = rintf(xc * INV_IN) * IN_SCALE;

        vf4 o;
#define COMP(c)                                                                \
        {                                                                      \
            const float vec = xq * qm.c;                                       \
            const float vcl = fminf(fmaxf(vec, 0.0f), 2.0f);                   \
            const float vq  = rintf(vcl * INV_L) * L_SCALE;                    \
            const float bcl = fminf(fmaxf(0.2f * p[r].c, 0.0f), 2.0f);         \
            const float bq  = rintf(bcl * INV_L) * L_SCALE;                    \
            const float rl  = fmaxf(vq + p[r].c - bq, 0.0f); /* relu */        \
            o.c = rintf(fminf(rl, 2.0f) * INV_L) * L_SCALE;  /* rl >= 0 */     \
        }
        COMP(x) COMP(y) COMP(z) COMP(w)
#undef COMP
        // NT store — minimize the write stream's allocation priority.
        __builtin_nontemporal_store(o, (vf4*)out + (long)(row0 + r) * N4 + t);
    }
}

extern "C" void kernel_launch(void* const* d_in, const int* in_sizes, int n_in,
                              void* d_out, int out_size, void* d_ws, size_t ws_size,
                              hipStream_t stream) {
    const float* x    = (const float*)d_in[0];   // [16384,1]
    const float* prev = (const float*)d_in[1];   // [16384,2048]
    const float* mask = (const float*)d_in[2];   // [1,2048]
    float* out = (float*)d_out;

    const int rows = in_sizes[1] / NN;           // 16384
    qdfr_fused<<<rows / RPB, 512, 0, stream>>>(x, prev, mask, out);
}

// Round 8
// 45.190 us; speedup vs baseline: 1.0755x; 1.0755x over previous
//
#include <hip/hip_runtime.h>

// QDFRCell fused: out = fq(relu(fq(xq*qmask,0,2) + prev - fq(0.2*prev,0,2)), 0, 2)
// x:[16384,1] f32, prev:[16384,2048] f32, mask:[1,2048] f32 -> out:[16384,2048] f32
//
// FINAL (round-4/6 config, best measured & reproduced): temporal prev loads +
// NT out stores. 45.1-45.3 us = 268.4 MB effective / 45.1 us = 5.95 TB/s =
// 94.6% of the 6.29 TB/s copy ceiling. Warm replays: FETCH 66 MB (MALL
// retains ~50% of prev at its fixed thrash-protection rate — NT-partition
// experiment proved hints can't raise it), WRITE 131 MB.
// Cache-policy space fully mapped:
//   NT/NT 48.5 | temporal/NT 45.1 (best) | NT/temporal 47.2 | partitioned 48.6
// Traffic is compulsory (bit-exact absmax=0.0); compute fully hidden.

constexpr int NN  = 2048;
constexpr int N4  = NN / 4;          // 512 float4 per row
constexpr int RPB = 8;               // rows per block

typedef float vf4 __attribute__((ext_vector_type(4)));

__global__ __launch_bounds__(512) void qdfr_fused(const float* __restrict__ x,
                                                  const float* __restrict__ prev,
                                                  const float* __restrict__ mask,
                                                  float* __restrict__ out) {
    constexpr float IN_SCALE = 0.497f / 255.0f;
    constexpr float INV_IN   = 1.0f / (0.497f / 255.0f);
    constexpr float L_SCALE  = 2.0f / 255.0f;
    constexpr float INV_L    = 1.0f / (2.0f / 255.0f);

    const int t    = threadIdx.x;
    const int row0 = blockIdx.x * RPB;

    // Temporal loads for prev (best measured); all 8 issued up front for MLP.
    vf4 p[RPB];
    #pragma unroll
    for (int r = 0; r < RPB; ++r)
        p[r] = ((const vf4*)prev)[(long)(row0 + r) * N4 + t];

    // Thread t consumes exactly mask4[t]; same registers feed the reduction.
    const vf4 m = ((const vf4*)mask)[t];

    float mn = fminf(fminf(m.x, m.y), fminf(m.z, m.w));
    float mx = fmaxf(fmaxf(m.x, m.y), fmaxf(m.z, m.w));
    #pragma unroll
    for (int d = 1; d < 64; d <<= 1) {
        mn = fminf(mn, __shfl_xor(mn, d));
        mx = fmaxf(mx, __shfl_xor(mx, d));
    }
    __shared__ float red[16];
    const int wave = t >> 6;
    if ((t & 63) == 0) { red[wave * 2] = mn; red[wave * 2 + 1] = mx; }
    __syncthreads();
    mn = red[0];
    mx = red[1];
    #pragma unroll
    for (int w = 1; w < 8; ++w) {
        mn = fminf(mn, red[w * 2]);
        mx = fmaxf(mx, red[w * 2 + 1]);
    }

    const float mscale = (mx - mn) / 255.0f;   // bit-exact vs reference expr
    const float minv   = 1.0f / mscale;

    // Quantize this thread's mask element once (shared by all 8 rows).
    vf4 qm;
    qm.x = rintf((m.x - mn) * minv) * mscale + mn;
    qm.y = rintf((m.y - mn) * minv) * mscale + mn;
    qm.z = rintf((m.z - mn) * minv) * mscale + mn;
    qm.w = rintf((m.w - mn) * minv) * mscale + mn;

    #pragma unroll
    for (int r = 0; r < RPB; ++r) {
        // fake_quant(x[row], 0, 0.497) — block-uniform scalar
        const float xv = x[row0 + r];
        const float xc = fminf(fmaxf(xv, 0.0f), 0.497f);
        const float xq = rintf(xc * INV_IN) * IN_SCALE;

        vf4 o;
#define COMP(c)                                                                \
        {                                                                      \
            const float vec = xq * qm.c;                                       \
            const float vcl = fminf(fmaxf(vec, 0.0f), 2.0f);                   \
            const float vq  = rintf(vcl * INV_L) * L_SCALE;                    \
            const float bcl = fminf(fmaxf(0.2f * p[r].c, 0.0f), 2.0f);         \
            const float bq  = rintf(bcl * INV_L) * L_SCALE;                    \
            const float rl  = fmaxf(vq + p[r].c - bq, 0.0f); /* relu */        \
            o.c = rintf(fminf(rl, 2.0f) * INV_L) * L_SCALE;  /* rl >= 0 */     \
        }
        COMP(x) COMP(y) COMP(z) COMP(w)
#undef COMP
        // NT store — keep the 134 MB write stream from evicting prev.
        __builtin_nontemporal_store(o, (vf4*)out + (long)(row0 + r) * N4 + t);
    }
}

extern "C" void kernel_launch(void* const* d_in, const int* in_sizes, int n_in,
                              void* d_out, int out_size, void* d_ws, size_t ws_size,
                              hipStream_t stream) {
    const float* x    = (const float*)d_in[0];   // [16384,1]
    const float* prev = (const float*)d_in[1];   // [16384,2048]
    const float* mask = (const float*)d_in[2];   // [1,2048]
    float* out = (float*)d_out;

    const int rows = in_sizes[1] / NN;           // 16384
    qdfr_fused<<<rows / RPB, 512, 0, stream>>>(x, prev, mask, out);
}